// Round 5
// baseline (298.317 us; speedup 1.0000x reference)
//
#include <hip/hip_runtime.h>

#define N_DIM 32
#define C_IN 64
#define C_OUT 64
#define T_DIM 288
#define V_DIM 25
#define TV 7200              // T_DIM * V_DIM
#define NROWS 9216           // N_DIM * T_DIM
#define NTV 230400           // N_DIM * TV  (BN reduction count per channel)
#define TOTAL 14745600       // N_DIM * C_OUT * TV
#define BN_EPS 1e-5f
#define NTILES 1800          // NTV / 128

// ws layout (float offsets)
#define WS_WINT 0            // wint[half][c][oo][2] : 2*64*32*2 = 8192 floats
#define WS_SUM 8192          // gsum[64]
#define WS_SQ  8256          // gsumsq[64]

// ---------------------------------------------------------------- K0: prep
__global__ __launch_bounds__(256) void prep_kernel(const float* __restrict__ W,
                                                   float* __restrict__ ws) {
  const int i = blockIdx.x * 256 + threadIdx.x;   // 0..8191
  if (blockIdx.x == 0 && threadIdx.x < 128) ws[WS_SUM + threadIdx.x] = 0.0f;
  // i = ((h*64 + c)*32 + oo)*2 + s
  const int s = i & 1;
  const int oo = (i >> 1) & 31;
  const int c = (i >> 6) & 63;
  const int h = i >> 12;
  const int o = h * 32 + oo;
  ws[WS_WINT + i] = W[o * 128 + s * 64 + c];  // s=0: fv weight, s=1: agg weight
}

// butterfly-transpose reduce: v[32] per lane (destroyed); every lane returns
// the sum of element (lane&31) across its 32-lane group.
__device__ __forceinline__ float reduce32_lane(float* v, int lane) {
#pragma unroll
  for (int s = 0; s < 5; ++s) {
    const int m = 1 << s;
    const bool up = (lane & m) != 0;
    const int pairs = 32 >> (s + 1);
#pragma unroll
    for (int q = 0; q < pairs; ++q) {
      const float keep = up ? v[2 * q + 1] : v[2 * q];
      const float send = up ? v[2 * q] : v[2 * q + 1];
      const float recv = __shfl_xor(send, m, 64);
      v[q] = keep + recv;
    }
  }
  return v[0];
}

// ---------------------------------------------------------------- K1: main
// 256 threads = 128 columns x 2 channel-halves; one 128-col tile per block.
// fv rows staged in LDS: 175 stager threads, 1 coalesced load/c, 2-deep
// register prefetch, double-buffered. Row stride 36 -> conflict-free b128.
__global__ __launch_bounds__(256, 4) void main_kernel(
    const float* __restrict__ fv, const float* __restrict__ adj,
    const float* __restrict__ wint, float* __restrict__ stats,
    float* __restrict__ out) {
  __shared__ __align__(16) float buf[2][7][36];
  __shared__ float lsum[C_OUT];
  __shared__ float lsq[C_OUT];

  const int tid = threadIdx.x;
  if (tid < 64) { lsum[tid] = 0.0f; lsq[tid] = 0.0f; }

  // wave-uniform channel-half selector (keeps weight address scalar -> s_load;
  // losing this was the R2 3x regression)
  const int half = __builtin_amdgcn_readfirstlane(tid) >> 7;
  const int lane = tid & 63;
  const float* __restrict__ wbase = wint + half * 4096;

  const int j0 = blockIdx.x << 7;
  const int col = j0 + (tid & 127);
  const int row = col / V_DIM;              // n*T + t
  const int y = col - row * V_DIM;
  const int rbase = j0 / V_DIM;
  const int rowoff = row - rbase;           // 0..6

  // adjacency column for this thread's joint
  float adjcol[V_DIM];
#pragma unroll
  for (int v = 0; v < V_DIM; ++v) adjcol[v] = adj[v * V_DIM + y];

  // staging setup: thread tid<175 owns element (rr, v) of the <=7x25 row block
  bool stager = false;
  int base_e = 0, srr = 0, sv = 0;
  if (tid < 175) {
    srr = tid / V_DIM;
    sv = tid - srr * V_DIM;
    const int Rg = rbase + srr;
    if (Rg < NROWS) {
      stager = true;
      const int n = Rg / T_DIM;
      const int t = Rg - n * T_DIM;
      base_e = n * (C_IN * TV) + t * V_DIM + sv;   // + c*TV per channel
    }
  }

  float acc[32];
#pragma unroll
  for (int oo = 0; oo < 32; ++oo) acc[oo] = 0.0f;

  // 2-deep prefetch pipeline
  float r0 = stager ? fv[base_e] : 0.0f;
  float r1 = stager ? fv[base_e + TV] : 0.0f;

#pragma unroll 1
  for (int c = 0; c < C_IN; ++c) {
    if (tid < 175) buf[c & 1][srr][sv] = r0;       // publish row block c
    r0 = r1;
    if (stager && c + 2 < C_IN) r1 = fv[base_e + (c + 2) * TV];
    __syncthreads();                               // row block c visible

    const float* __restrict__ br = &buf[c & 1][rowoff][0];
    const float x = br[y];
    const float4* __restrict__ b4 = reinterpret_cast<const float4*>(br);
    float xa0 = 0.f, xa1 = 0.f, xa2 = 0.f, xa3 = 0.f;
#pragma unroll
    for (int q = 0; q < 6; ++q) {
      const float4 f = b4[q];
      xa0 = fmaf(f.x, adjcol[4 * q + 0], xa0);
      xa1 = fmaf(f.y, adjcol[4 * q + 1], xa1);
      xa2 = fmaf(f.z, adjcol[4 * q + 2], xa2);
      xa3 = fmaf(f.w, adjcol[4 * q + 3], xa3);
    }
    xa0 = fmaf(br[24], adjcol[24], xa0);
    const float xa = (xa0 + xa1) + (xa2 + xa3);

    // 64 contiguous wave-uniform floats -> s_load + SGPR-operand fma
    const float* __restrict__ w = wbase + c * 64;
#pragma unroll
    for (int oo = 0; oo < 32; ++oo)
      acc[oo] = fmaf(x, w[oo * 2], fmaf(xa, w[oo * 2 + 1], acc[oo]));
  }

  // write pre-BN output (channels half*32 .. half*32+31)
  {
    const int n = row / T_DIM;
    const int t = row - n * T_DIM;
    float* op = out + ((size_t)n * C_OUT + half * 32) * TV + t * V_DIM + y;
#pragma unroll
    for (int oo = 0; oo < 32; ++oo) op[oo * TV] = acc[oo];
  }

  // per-wave channel sums / sumsq -> LDS -> one global atomic set per block
  float sq[32];
#pragma unroll
  for (int i = 0; i < 32; ++i) sq[i] = acc[i] * acc[i];
  float s = reduce32_lane(acc, lane);              // destroys acc
  s += __shfl_xor(s, 32, 64);
  float q = reduce32_lane(sq, lane);
  q += __shfl_xor(q, 32, 64);

  if (lane < 32) {
    atomicAdd(&lsum[half * 32 + lane], s);
    atomicAdd(&lsq[half * 32 + lane], q);
  }
  __syncthreads();
  if (tid < 64) {
    atomicAdd(&stats[tid], lsum[tid]);
    atomicAdd(&stats[64 + tid], lsq[tid]);
  }
}

// ---------------------------------------------------------------- K2: BN+ReLU
__global__ __launch_bounds__(256) void bn_kernel(const float* __restrict__ stats,
                                                 const float* __restrict__ gamma,
                                                 const float* __restrict__ beta,
                                                 float* __restrict__ out) {
  __shared__ float s_scale[C_OUT];
  __shared__ float s_shift[C_OUT];
  const int tid = threadIdx.x;
  if (tid < C_OUT) {
    const float inv = 1.0f / (float)NTV;
    const float mean = stats[tid] * inv;
    const float var = fmaf(stats[64 + tid], inv, -mean * mean);
    const float sc = gamma[tid] * rsqrtf(var + BN_EPS);
    s_scale[tid] = sc;
    s_shift[tid] = fmaf(-mean, sc, beta[tid]);
  }
  __syncthreads();

  float4* o4 = reinterpret_cast<float4*>(out);
  const int total4 = TOTAL / 4;               // TV%4==0 so channel is
  const int stride = gridDim.x * blockDim.x;  // constant within each float4
  for (int i = blockIdx.x * blockDim.x + tid; i < total4; i += stride) {
    float4 v = o4[i];
    const int o = (i / 1800) & 63;            // 1800 = TV/4
    const float sc = s_scale[o];
    const float sh = s_shift[o];
    v.x = fmaxf(fmaf(v.x, sc, sh), 0.0f);
    v.y = fmaxf(fmaf(v.y, sc, sh), 0.0f);
    v.z = fmaxf(fmaf(v.z, sc, sh), 0.0f);
    v.w = fmaxf(fmaf(v.w, sc, sh), 0.0f);
    o4[i] = v;
  }
}

// ---------------------------------------------------------------- launcher
extern "C" void kernel_launch(void* const* d_in, const int* in_sizes, int n_in,
                              void* d_out, int out_size, void* d_ws, size_t ws_size,
                              hipStream_t stream) {
  const float* fv = (const float*)d_in[0];
  const float* adj = (const float*)d_in[1];
  const float* W = (const float*)d_in[2];
  // d_in[3] = b : exactly cancelled by training-mode BN mean subtraction
  const float* gamma = (const float*)d_in[4];
  const float* beta = (const float*)d_in[5];
  float* out = (float*)d_out;
  float* ws = (float*)d_ws;

  hipLaunchKernelGGL(prep_kernel, dim3(32), dim3(256), 0, stream, W, ws);
  hipLaunchKernelGGL(main_kernel, dim3(NTILES), dim3(256), 0, stream,
                     fv, adj, ws + WS_WINT, ws + WS_SUM, out);
  hipLaunchKernelGGL(bn_kernel, dim3(2048), dim3(256), 0, stream,
                     ws + WS_SUM, gamma, beta, out);
}